// Round 11
// baseline (748.600 us; speedup 1.0000x reference)
//
#include <hip/hip_runtime.h>
#include <hip/hip_bf16.h>

// Geo2Vec fused MLP, bf16 MFMA. Round 11: 512-thread blocks, BM=32, 52KB LDS
// -> 3 independent blocks/CU (24 waves = 6/SIMD, decorrelated barriers) and a
// real VGPR budget (512-thr blocks get ~96-112 regs vs the 64-reg cap that
// strangled R5-R10's 1024-thr blocks). 8 waves = 8 col-groups x (32 rows, 32
// cols); depth-2 A + depth-3 B register pipelines + cross-gemm B prefetch.

typedef __attribute__((ext_vector_type(8))) __bf16 bfv8;
typedef __attribute__((ext_vector_type(8))) short s16x8;
typedef __attribute__((ext_vector_type(4))) float f32x4;
typedef __attribute__((ext_vector_type(4))) int i32x4;
typedef __attribute__((ext_vector_type(2))) int i32x2;

__device__ __forceinline__ short f2bf(float f) {
  unsigned u = __builtin_bit_cast(unsigned, f);
  u = (u + 0x7fffu + ((u >> 16) & 1u)) >> 16;
  return (short)u;
}
__device__ __forceinline__ float bf2f(short s) {
  unsigned u = ((unsigned)(unsigned short)s) << 16;
  return __builtin_bit_cast(float, u);
}
// Swizzle: conflict-free for 16-row A-reads and 4-row-group epilogue writes.
__device__ __forceinline__ int swzaddr(int base, int stride, int row, int colbyte) {
  return base + row * stride + (colbyte ^ (((row & 7) << 4) ^ ((row & 8) << 2)));
}
// LDS-visibility barrier that does NOT drain vmcnt (keeps B prefetch in flight).
__device__ __forceinline__ void ldsbar() {
  __builtin_amdgcn_sched_barrier(0);
  asm volatile("s_waitcnt lgkmcnt(0)");
  __builtin_amdgcn_s_barrier();
  __builtin_amdgcn_sched_barrier(0);
}

// ---------------- weight pack: fp32 row-major (K,256) -> bf16 B-frag-major ----
// packet p = (kt*16 + nt)*64 + lane ; dst[p*8+i] = W[kt*32 + 8*(lane>>4) + i][nt*16 + (lane&15)]
__global__ void pack_weights_kernel(const float* __restrict__ W1a, const float* __restrict__ W1b,
                                    const float* __restrict__ Wa, const float* __restrict__ Wb,
                                    short* __restrict__ ws) {
  int p = blockIdx.x * blockDim.x + threadIdx.x;
  const int P1 = 10240;           // W1a: 10 kt * 16 nt * 64
  const int P2 = P1 + 8192;       // W1b
  const int P3 = P2 + 8 * 18432;  // Wa
  const int P4 = P3 + 8 * 8192;   // Wb
  if (p >= P4) return;
  const float* src;
  int q;
  if (p < P1)      { src = W1a; q = p; }
  else if (p < P2) { src = W1b; q = p - P1; }
  else if (p < P3) { q = p - P2; int l = q / 18432; q -= l * 18432; src = Wa + l * 147456; }
  else             { q = p - P3; int l = q / 8192;  q -= l * 8192;  src = Wb + l * 65536; }
  const int lane = q & 63, t = q >> 6, nt = t & 15, kt = t >> 4;
  const int k0 = kt * 32 + ((lane >> 4) << 3);
  const int n  = (nt << 4) + (lane & 15);
  short* dst = ws + (size_t)p * 8;
#pragma unroll
  for (int i = 0; i < 8; ++i) dst[i] = f2bf(src[(size_t)(k0 + i) * 256 + n]);
}

// ---------------- fused MLP ----------------
// LDS (bytes): xyz [0,20480) stride 640 ; x [20480,36864) stride 512 ;
//              t [36864,53248) stride 512  (52 KB -> 3 blocks/CU)
#define XB 20480
#define TB 36864

struct BPre { bfv8 b0, b1; };
struct AFrag { bfv8 r0, r1; };

__device__ __forceinline__ bfv8 bfrag(const short* __restrict__ wp, int kt, int nt, int lane) {
  return *(const bfv8*)(wp + (((size_t)(kt * 16 + nt) * 64 + lane) << 3));
}

template<int SPLITKT>
__device__ __forceinline__ AFrag aload(const short* lds,
    int a1Base, int a1S, int a2Base, int a2S, int kt, int lo, int hi)
{
  const int base  = (kt < SPLITKT) ? a1Base : a2Base;
  const int strd  = (kt < SPLITKT) ? a1S : a2S;
  const int kk    = (kt < SPLITKT) ? kt : kt - SPLITKT;
  const int kbyte = kk * 64 + (hi << 4);
  AFrag f;
  f.r0 = *(const bfv8*)((const char*)lds + swzaddr(base, strd,       lo, kbyte));
  f.r1 = *(const bfv8*)((const char*)lds + swzaddr(base, strd, 16 + lo, kbyte));
  return f;
}

template<int NKT, int SPLITKT, bool LEAKY>
__device__ __forceinline__ BPre do_gemm(short* lds,
    int a1Base, int a1S, int a2Base, int a2S,
    const short* __restrict__ wp, const short* __restrict__ wpn,
    const float* __restrict__ bias, int outBase,
    int wc, int lane, BPre pre)
{
  const int lo = lane & 15, hi = lane >> 4;
  const int ntb = wc << 1;   // 2 coltiles per wave (32 cols)
  const float bv0 = bias[(ntb << 4) + lo];
  const float bv1 = bias[(ntb << 4) + 16 + lo];
  f32x4 acc[2][2];
#pragma unroll
  for (int r = 0; r < 2; ++r) { acc[r][0] = (f32x4)0.f; acc[r][1] = (f32x4)0.f; }

  // B: 3-deep rotation (slot i%3). A: 2-deep (slot i&1).
  bfv8 bst[3][2];
  AFrag ast[2];
  bst[0][0] = pre.b0; bst[0][1] = pre.b1;
  if (NKT > 1) {
    bst[1][0] = bfrag(wp, 1, ntb, lane);
    bst[1][1] = bfrag(wp, 1, ntb + 1, lane);
  }
  ast[0] = aload<SPLITKT>(lds, a1Base, a1S, a2Base, a2S, 0, lo, hi);
  BPre nxt;

#pragma unroll
  for (int i = 0; i < NKT; ++i) {
    if (i + 2 < NKT) {
      bst[(i + 2) % 3][0] = bfrag(wp, i + 2, ntb, lane);
      bst[(i + 2) % 3][1] = bfrag(wp, i + 2, ntb + 1, lane);
    } else if (i + 2 == NKT) {  // start next gemm's first B frags early
      nxt.b0 = bfrag(wpn, 0, ntb, lane);
      nxt.b1 = bfrag(wpn, 0, ntb + 1, lane);
    }
    if (i + 1 < NKT) ast[(i + 1) & 1] = aload<SPLITKT>(lds, a1Base, a1S, a2Base, a2S, i + 1, lo, hi);
    __builtin_amdgcn_s_setprio(1);
    acc[0][0] = __builtin_amdgcn_mfma_f32_16x16x32_bf16(ast[i & 1].r0, bst[i % 3][0], acc[0][0], 0, 0, 0);
    acc[0][1] = __builtin_amdgcn_mfma_f32_16x16x32_bf16(ast[i & 1].r0, bst[i % 3][1], acc[0][1], 0, 0, 0);
    acc[1][0] = __builtin_amdgcn_mfma_f32_16x16x32_bf16(ast[i & 1].r1, bst[i % 3][0], acc[1][0], 0, 0, 0);
    acc[1][1] = __builtin_amdgcn_mfma_f32_16x16x32_bf16(ast[i & 1].r1, bst[i % 3][1], acc[1][1], 0, 0, 0);
    __builtin_amdgcn_s_setprio(0);
  }
  // epilogue: bias + (leaky) + bf16 round -> LDS
#pragma unroll
  for (int rt = 0; rt < 2; ++rt)
#pragma unroll
    for (int ct = 0; ct < 2; ++ct)
#pragma unroll
      for (int rr = 0; rr < 4; ++rr) {
        const int orow = (rt << 4) + (hi << 2) + rr;
        const int col  = ((ntb + ct) << 4) + lo;
        float v = acc[rt][ct][rr] + (ct ? bv1 : bv0);
        if (LEAKY) v = (v >= 0.f) ? v : 0.01f * v;
        *(short*)((char*)lds + swzaddr(outBase, 512, orow, col << 1)) = f2bf(v);
      }
  return nxt;
}

__launch_bounds__(512, 1)
__global__ void geo2vec_kernel(const float* __restrict__ xy, const int* __restrict__ idx,
    const float* __restrict__ emb,
    const float* __restrict__ b1a, const float* __restrict__ b1b,
    const float* __restrict__ ba, const float* __restrict__ bb,
    const float* __restrict__ W2, const float* __restrict__ b2,
    const short* __restrict__ wp, float* __restrict__ out)
{
  __shared__ short lds[26624];  // 52 KB
  const int tid = threadIdx.x;
  const int wc = tid >> 6, lane = tid & 63;

  // issue first gemm's B stage-0 loads immediately: hide under prologue trig
  BPre pre;
  pre.b0 = bfrag(wp, 0, (wc << 1), lane);
  pre.b1 = bfrag(wp, 0, (wc << 1) + 1, lane);

  // ---- prologue: pos-encode + gather z -> xyz tile (32 x 320 bf16) ----
  {
    const int g = tid >> 4, j = tid & 15;  // 16 threads per row, 32 rows
    const int row = blockIdx.x * 32 + g;
    const float xv = xy[2 * row], yv = xy[2 * row + 1];
    const float rv = sqrtf(xv * xv + yv * yv);
    union { short sh[4]; i32x2 v; } tmp;
#pragma unroll
    for (int i = 0; i < 4; ++i) {
      const int c = 4 * j + i;
      float fv;
      if (c < 2)       fv = c ? yv : xv;
      else if (c < 22) { int m = c - 2;  float f = 1.0f + (5.0f / 9.0f) * (m >> 1); fv = sinf(((m & 1) ? yv : xv) * f); }
      else if (c < 42) { int m = c - 22; float f = 1.0f + (5.0f / 9.0f) * (m >> 1); fv = cosf(((m & 1) ? yv : xv) * f); }
      else if (c < 44) fv = (c == 42) ? xv : yv;
      else if (c < 54) fv = sinf(rv * (1.0f + (5.0f / 9.0f) * (c - 44)));
      else             fv = cosf(rv * (1.0f + (5.0f / 9.0f) * (c - 54)));
      tmp.sh[i] = f2bf(fv);
    }
    *(i32x2*)((char*)lds + swzaddr(0, 640, g, j << 3)) = tmp.v;
    const float* zr = emb + (size_t)(unsigned)idx[row] * 256;
#pragma unroll
    for (int c8 = 0; c8 < 2; ++c8) {
      const int cel = j * 16 + c8 * 8;
      const float4 f0 = *(const float4*)(zr + cel);
      const float4 f1 = *(const float4*)(zr + cel + 4);
      union { short sh[8]; i32x4 v; } t2;
      t2.sh[0] = f2bf(f0.x); t2.sh[1] = f2bf(f0.y); t2.sh[2] = f2bf(f0.z); t2.sh[3] = f2bf(f0.w);
      t2.sh[4] = f2bf(f1.x); t2.sh[5] = f2bf(f1.y); t2.sh[6] = f2bf(f1.z); t2.sh[7] = f2bf(f1.w);
      *(i32x4*)((char*)lds + swzaddr(0, 640, g, (64 + cel) << 1)) = t2.v;
    }
  }
  ldsbar();

  // layer 1
  pre = do_gemm<10, 10, true >(lds, 0, 640, 0, 640,   wp,         wp + 81920,  b1a, TB, wc, lane, pre);
  ldsbar();
  pre = do_gemm<8,  8,  false>(lds, TB, 512, TB, 512, wp + 81920, wp + 147456, b1b, XB, wc, lane, pre);
  ldsbar();
  // 8 mid layers
  for (int l = 0; l < 8; ++l) {
    const short* wa = wp + 147456 + l * 147456;
    const short* wb = wp + 1327104 + l * 65536;
    const short* wan = (l < 7) ? (wa + 147456) : wp;  // dummy (valid mem) on last layer
    pre = do_gemm<18, 10, true >(lds, 0, 640, XB, 512,  wa, wb,  ba + l * 256, TB, wc, lane, pre);
    ldsbar();
    pre = do_gemm<8,  8,  false>(lds, TB, 512, TB, 512, wb, wan, bb + l * 256, XB, wc, lane, pre);
    ldsbar();
  }
  // final: out = x @ W2 + b2 ; 16 threads per row, width-16 shuffle reduce
  {
    const int r = tid >> 4, j = tid & 15;
    float sum = 0.f;
#pragma unroll
    for (int h = 0; h < 2; ++h) {
      const int cb = 32 * j + 16 * h;
      const s16x8 v = *(const s16x8*)((const char*)lds + swzaddr(XB, 512, r, cb));
      const int c0 = 16 * j + 8 * h;
      const float4 w0 = *(const float4*)(W2 + c0);
      const float4 w1 = *(const float4*)(W2 + c0 + 4);
      sum += bf2f(v[0]) * w0.x + bf2f(v[1]) * w0.y + bf2f(v[2]) * w0.z + bf2f(v[3]) * w0.w;
      sum += bf2f(v[4]) * w1.x + bf2f(v[5]) * w1.y + bf2f(v[6]) * w1.z + bf2f(v[7]) * w1.w;
    }
    sum += __shfl_xor(sum, 1); sum += __shfl_xor(sum, 2);
    sum += __shfl_xor(sum, 4); sum += __shfl_xor(sum, 8);
    if (j == 0) out[blockIdx.x * 32 + r] = sum + b2[0];
  }
}

extern "C" void kernel_launch(void* const* d_in, const int* in_sizes, int n_in,
                              void* d_out, int out_size, void* d_ws, size_t ws_size,
                              hipStream_t stream) {
  const float* xy  = (const float*)d_in[0];
  const int*   idx = (const int*)d_in[1];
  const float* emb = (const float*)d_in[2];
  const float* W1a = (const float*)d_in[3];
  const float* b1a = (const float*)d_in[4];
  const float* W1b = (const float*)d_in[5];
  const float* b1b = (const float*)d_in[6];
  const float* Wa  = (const float*)d_in[7];
  const float* ba  = (const float*)d_in[8];
  const float* Wb  = (const float*)d_in[9];
  const float* bb  = (const float*)d_in[10];
  const float* W2  = (const float*)d_in[11];
  const float* b2  = (const float*)d_in[12];
  short* ws = (short*)d_ws;
  const int B = in_sizes[1];

  hipLaunchKernelGGL(pack_weights_kernel, dim3(904), dim3(256), 0, stream,
                     W1a, W1b, Wa, Wb, ws);
  hipLaunchKernelGGL(geo2vec_kernel, dim3(B / 32), dim3(512), 0, stream,
                     xy, idx, emb, b1a, b1b, ba, bb, W2, b2, ws, (float*)d_out);
}

// Round 12
// 622.388 us; speedup vs baseline: 1.2028x; 1.2028x over previous
//
#include <hip/hip_runtime.h>
#include <hip/hip_bf16.h>

// Geo2Vec fused MLP, bf16 MFMA. Round 12: R10 structure (1024 thr, 16 waves,
// 2x8 wave grid, 32x32 tiles, 2-deep A/B pipelines) with the VALU stripped out
// of the hot loop:
//  - B loads via wave-uniform SGPR base (readfirstlane) + constant voffset
//  - A loads via precomputed even/odd swizzle bases; per-kt offset = immediate
//  - epilogue: interleaved-col weight packing -> v_cvt_pk_bf16_f32 + b32 store
//  - leaky as fmax(v, 0.01v); bias as one float2 load

typedef __attribute__((ext_vector_type(8))) __bf16 bfv8;
typedef __attribute__((ext_vector_type(8))) short s16x8;
typedef __attribute__((ext_vector_type(4))) float f32x4;
typedef __attribute__((ext_vector_type(4))) int i32x4;
typedef __attribute__((ext_vector_type(2))) int i32x2;

__device__ __forceinline__ short f2bf(float f) {
  unsigned u = __builtin_bit_cast(unsigned, f);
  u = (u + 0x7fffu + ((u >> 16) & 1u)) >> 16;
  return (short)u;
}
__device__ __forceinline__ float bf2f(short s) {
  unsigned u = ((unsigned)(unsigned short)s) << 16;
  return __builtin_bit_cast(float, u);
}
// Swizzle: conflict-free for 16-row A-reads and epilogue writes.
__device__ __forceinline__ int swzaddr(int base, int stride, int row, int colbyte) {
  return base + row * stride + (colbyte ^ (((row & 7) << 4) ^ ((row & 8) << 2)));
}
// LDS-visibility barrier that does NOT drain vmcnt (keeps B prefetch in flight).
__device__ __forceinline__ void ldsbar() {
  __builtin_amdgcn_sched_barrier(0);
  asm volatile("s_waitcnt lgkmcnt(0)");
  __builtin_amdgcn_s_barrier();
  __builtin_amdgcn_sched_barrier(0);
}

// ---------------- weight pack ----------------
// fp32 row-major (K,256) -> bf16 B-frag-major with INTERLEAVED columns:
// packet p = (kt*16 + nt)*64 + lane ; frag column j=lane&15 maps to actual
// column n = (nt>>1)*32 + 2*j + (nt&1)  (even/odd interleave within 32-col
// wave group so ct=0/1 outputs are memory-adjacent -> cvt_pk + b32 stores).
__global__ void pack_weights_kernel(const float* __restrict__ W1a, const float* __restrict__ W1b,
                                    const float* __restrict__ Wa, const float* __restrict__ Wb,
                                    short* __restrict__ ws) {
  int p = blockIdx.x * blockDim.x + threadIdx.x;
  const int P1 = 10240;           // W1a: 10 kt * 16 nt * 64
  const int P2 = P1 + 8192;       // W1b
  const int P3 = P2 + 8 * 18432;  // Wa
  const int P4 = P3 + 8 * 8192;   // Wb
  if (p >= P4) return;
  const float* src;
  int q;
  if (p < P1)      { src = W1a; q = p; }
  else if (p < P2) { src = W1b; q = p - P1; }
  else if (p < P3) { q = p - P2; int l = q / 18432; q -= l * 18432; src = Wa + l * 147456; }
  else             { q = p - P3; int l = q / 8192;  q -= l * 8192;  src = Wb + l * 65536; }
  const int lane = q & 63, t = q >> 6, nt = t & 15, kt = t >> 4;
  const int k0 = kt * 32 + ((lane >> 4) << 3);
  const int n  = ((nt >> 1) << 5) + ((lane & 15) << 1) + (nt & 1);
  short* dst = ws + (size_t)p * 8;
#pragma unroll
  for (int i = 0; i < 8; ++i) dst[i] = f2bf(src[(size_t)(k0 + i) * 256 + n]);
}

// ---------------- fused MLP ----------------
// LDS (bytes): xyz [0,40960) stride 640 ; x [40960,73728) stride 512 ;
//              t [73728,106496) stride 512
struct BPre { bfv8 b0, b1; };
struct AFrag { bfv8 r0, r1; };

__device__ __forceinline__ bfv8 bfrag(const short* __restrict__ wp, int kt, int nt, int lane) {
  const short* base = wp + (((size_t)(kt * 16 + nt)) << 9);  // wave-uniform
  return *(const bfv8*)(base + (lane << 3));                 // lane offset
}

template<int NKT, int SPLITKT, bool LEAKY>
__device__ __forceinline__ BPre do_gemm(short* lds,
    int a1Base, int a1S, int a2Base, int a2S,
    const short* __restrict__ wp, const short* __restrict__ wpn,
    const float* __restrict__ bias, int outBase,
    int wrb, int wc, int lane, BPre pre)
{
  const int lo = lane & 15, hi = lane >> 4;
  const int ntb = wc << 1;
  // bias for interleaved cols (2*lo, 2*lo+1) of this wave's 32-col group
  const float2 bv = *(const float2*)(bias + (wc << 5) + (lo << 1));
  f32x4 acc[2][2];
#pragma unroll
  for (int r = 0; r < 2; ++r) { acc[r][0] = (f32x4)0.f; acc[r][1] = (f32x4)0.f; }

  // Precomputed A bases: swizzle xor decomposes as base[kk&1] + (kk>>1)*128.
  // xr depends only on lo (wrb is a multiple of 32 -> row&7, row&8 from lo).
  const int xr  = ((lo & 7) << 4) ^ ((lo & 8) << 2);
  const int hib = hi << 4;
  const char* A1E = (const char*)lds + a1Base + (wrb + lo) * a1S + ((      hib) ^ xr);
  const char* A1O = (const char*)lds + a1Base + (wrb + lo) * a1S + ((64 + hib) ^ xr);
  const char* A2E = (const char*)lds + a2Base + (wrb + lo) * a2S + ((      hib) ^ xr);
  const char* A2O = (const char*)lds + a2Base + (wrb + lo) * a2S + ((64 + hib) ^ xr);

  bfv8 bst[2][2];
  AFrag ast[2];
  bst[0][0] = pre.b0; bst[0][1] = pre.b1;
  ast[0].r0 = *(const bfv8*)(A1E);
  ast[0].r1 = *(const bfv8*)(A1E + (a1S << 4));
  BPre nxt;

#pragma unroll
  for (int i = 0; i < NKT; ++i) {
    if (i + 1 < NKT) {
      bst[(i + 1) & 1][0] = bfrag(wp, i + 1, ntb, lane);
      bst[(i + 1) & 1][1] = bfrag(wp, i + 1, ntb + 1, lane);
      const int kt = i + 1;
      const int kk = (kt < SPLITKT) ? kt : kt - SPLITKT;
      const char* b = (kt < SPLITKT) ? ((kk & 1) ? A1O : A1E) : ((kk & 1) ? A2O : A2E);
      const int s  = (kt < SPLITKT) ? a1S : a2S;
      ast[(i + 1) & 1].r0 = *(const bfv8*)(b + (kk >> 1) * 128);
      ast[(i + 1) & 1].r1 = *(const bfv8*)(b + (kk >> 1) * 128 + (s << 4));
    } else {  // last iter: start next gemm's first B frags (fly over epilogue+barrier)
      nxt.b0 = bfrag(wpn, 0, ntb, lane);
      nxt.b1 = bfrag(wpn, 0, ntb + 1, lane);
    }
    __builtin_amdgcn_s_setprio(1);
    acc[0][0] = __builtin_amdgcn_mfma_f32_16x16x32_bf16(ast[i & 1].r0, bst[i & 1][0], acc[0][0], 0, 0, 0);
    acc[0][1] = __builtin_amdgcn_mfma_f32_16x16x32_bf16(ast[i & 1].r0, bst[i & 1][1], acc[0][1], 0, 0, 0);
    acc[1][0] = __builtin_amdgcn_mfma_f32_16x16x32_bf16(ast[i & 1].r1, bst[i & 1][0], acc[1][0], 0, 0, 0);
    acc[1][1] = __builtin_amdgcn_mfma_f32_16x16x32_bf16(ast[i & 1].r1, bst[i & 1][1], acc[1][1], 0, 0, 0);
    __builtin_amdgcn_s_setprio(0);
  }
  // epilogue: bias + leaky + cvt_pk(2 bf16) -> one b32 store per pair
#pragma unroll
  for (int rt = 0; rt < 2; ++rt)
#pragma unroll
    for (int rr = 0; rr < 4; ++rr) {
      float v0 = acc[rt][0][rr] + bv.x;
      float v1 = acc[rt][1][rr] + bv.y;
      if (LEAKY) { v0 = fmaxf(v0, 0.01f * v0); v1 = fmaxf(v1, 0.01f * v1); }
      unsigned pk;
      asm("v_cvt_pk_bf16_f32 %0, %1, %2" : "=v"(pk) : "v"(v0), "v"(v1));
      const int orow = wrb + (rt << 4) + (hi << 2) + rr;
      *(unsigned*)((char*)lds + swzaddr(outBase, 512, orow, (wc << 6) + (lo << 2))) = pk;
    }
  return nxt;
}

__launch_bounds__(1024, 1)
__global__ void geo2vec_kernel(const float* __restrict__ xy, const int* __restrict__ idx,
    const float* __restrict__ emb,
    const float* __restrict__ b1a, const float* __restrict__ b1b,
    const float* __restrict__ ba, const float* __restrict__ bb,
    const float* __restrict__ W2, const float* __restrict__ b2,
    const short* __restrict__ wp, float* __restrict__ out)
{
  __shared__ short lds[53248];  // 104 KB
  const int tid = threadIdx.x;
  const int wave = tid >> 6, lane = tid & 63;
  const int wr = wave >> 3;
  const int wc = __builtin_amdgcn_readfirstlane(wave & 7);  // force SGPR -> saddr B loads
  const int wrb = wr << 5;

  // issue first gemm's B stage-0 loads immediately: hide under prologue trig
  BPre pre;
  pre.b0 = bfrag(wp, 0, (wc << 1), lane);
  pre.b1 = bfrag(wp, 0, (wc << 1) + 1, lane);

  // ---- prologue: pos-encode + gather z -> xyz tile (64 x 320 bf16) ----
  {
    const int g = tid >> 4, j = tid & 15;  // 16 threads per row
    const int row = blockIdx.x * 64 + g;
    const float xv = xy[2 * row], yv = xy[2 * row + 1];
    const float rv = sqrtf(xv * xv + yv * yv);
    union { short sh[4]; i32x2 v; } tmp;
#pragma unroll
    for (int i = 0; i < 4; ++i) {
      const int c = 4 * j + i;
      float fv;
      if (c < 2)       fv = c ? yv : xv;
      else if (c < 22) { int m = c - 2;  float f = 1.0f + (5.0f / 9.0f) * (m >> 1); fv = sinf(((m & 1) ? yv : xv) * f); }
      else if (c < 42) { int m = c - 22; float f = 1.0f + (5.0f / 9.0f) * (m >> 1); fv = cosf(((m & 1) ? yv : xv) * f); }
      else if (c < 44) fv = (c == 42) ? xv : yv;
      else if (c < 54) fv = sinf(rv * (1.0f + (5.0f / 9.0f) * (c - 44)));
      else             fv = cosf(rv * (1.0f + (5.0f / 9.0f) * (c - 54)));
      tmp.sh[i] = f2bf(fv);
    }
    *(i32x2*)((char*)lds + swzaddr(0, 640, g, j << 3)) = tmp.v;
    const float* zr = emb + (size_t)(unsigned)idx[row] * 256;
#pragma unroll
    for (int c8 = 0; c8 < 2; ++c8) {
      const int cel = j * 16 + c8 * 8;
      const float4 f0 = *(const float4*)(zr + cel);
      const float4 f1 = *(const float4*)(zr + cel + 4);
      union { short sh[8]; i32x4 v; } t2;
      t2.sh[0] = f2bf(f0.x); t2.sh[1] = f2bf(f0.y); t2.sh[2] = f2bf(f0.z); t2.sh[3] = f2bf(f0.w);
      t2.sh[4] = f2bf(f1.x); t2.sh[5] = f2bf(f1.y); t2.sh[6] = f2bf(f1.z); t2.sh[7] = f2bf(f1.w);
      *(i32x4*)((char*)lds + swzaddr(0, 640, g, (64 + cel) << 1)) = t2.v;
    }
  }
  ldsbar();

  // layer 1
  pre = do_gemm<10, 10, true >(lds, 0, 640, 0, 640,         wp,         wp + 81920,  b1a, 73728, wrb, wc, lane, pre);
  ldsbar();
  pre = do_gemm<8,  8,  false>(lds, 73728, 512, 73728, 512, wp + 81920, wp + 147456, b1b, 40960, wrb, wc, lane, pre);
  ldsbar();
  // 8 mid layers
  for (int l = 0; l < 8; ++l) {
    const short* wa = wp + 147456 + l * 147456;
    const short* wb = wp + 1327104 + l * 65536;
    const short* wan = (l < 7) ? (wa + 147456) : wp;  // dummy (valid mem) on last layer
    pre = do_gemm<18, 10, true >(lds, 0, 640, 40960, 512,     wa, wb,  ba + l * 256, 73728, wrb, wc, lane, pre);
    ldsbar();
    pre = do_gemm<8,  8,  false>(lds, 73728, 512, 73728, 512, wb, wan, bb + l * 256, 40960, wrb, wc, lane, pre);
    ldsbar();
  }
  // final: out = x @ W2 + b2 ; 16 threads per row, width-16 shuffle reduce
  {
    const int r = tid >> 4, j = tid & 15;
    float sum = 0.f;
#pragma unroll
    for (int h = 0; h < 2; ++h) {
      const int cb = 32 * j + 16 * h;
      const s16x8 v = *(const s16x8*)((const char*)lds + swzaddr(40960, 512, r, cb));
      const int c0 = 16 * j + 8 * h;
      const float4 w0 = *(const float4*)(W2 + c0);
      const float4 w1 = *(const float4*)(W2 + c0 + 4);
      sum += bf2f(v[0]) * w0.x + bf2f(v[1]) * w0.y + bf2f(v[2]) * w0.z + bf2f(v[3]) * w0.w;
      sum += bf2f(v[4]) * w1.x + bf2f(v[5]) * w1.y + bf2f(v[6]) * w1.z + bf2f(v[7]) * w1.w;
    }
    sum += __shfl_xor(sum, 1); sum += __shfl_xor(sum, 2);
    sum += __shfl_xor(sum, 4); sum += __shfl_xor(sum, 8);
    if (j == 0) out[blockIdx.x * 64 + r] = sum + b2[0];
  }
}

extern "C" void kernel_launch(void* const* d_in, const int* in_sizes, int n_in,
                              void* d_out, int out_size, void* d_ws, size_t ws_size,
                              hipStream_t stream) {
  const float* xy  = (const float*)d_in[0];
  const int*   idx = (const int*)d_in[1];
  const float* emb = (const float*)d_in[2];
  const float* W1a = (const float*)d_in[3];
  const float* b1a = (const float*)d_in[4];
  const float* W1b = (const float*)d_in[5];
  const float* b1b = (const float*)d_in[6];
  const float* Wa  = (const float*)d_in[7];
  const float* ba  = (const float*)d_in[8];
  const float* Wb  = (const float*)d_in[9];
  const float* bb  = (const float*)d_in[10];
  const float* W2  = (const float*)d_in[11];
  const float* b2  = (const float*)d_in[12];
  short* ws = (short*)d_ws;
  const int B = in_sizes[1];

  hipLaunchKernelGGL(pack_weights_kernel, dim3(904), dim3(256), 0, stream,
                     W1a, W1b, Wa, Wb, ws);
  hipLaunchKernelGGL(geo2vec_kernel, dim3(B / 64), dim3(1024), 0, stream,
                     xy, idx, emb, b1a, b1b, ba, bb, W2, b2, ws, (float*)d_out);
}

// Round 13
// 598.082 us; speedup vs baseline: 1.2517x; 1.0406x over previous
//
#include <hip/hip_runtime.h>
#include <hip/hip_bf16.h>

// Geo2Vec fused MLP, bf16 MFMA. Round 13: R12 lean loop + ZERO whole-block
// barriers. The block's two row-halves (waves 0-7 = rows 0-31, waves 8-15 =
// rows 32-63) are fully independent after the prologue; each half syncs via a
// monotonic LDS counter soft-barrier (ds_add + spin). Halves drift -> one
// half's MFMA phase covers the other's load phase (breaks barrier lockstep).

typedef __attribute__((ext_vector_type(8))) __bf16 bfv8;
typedef __attribute__((ext_vector_type(8))) short s16x8;
typedef __attribute__((ext_vector_type(4))) float f32x4;
typedef __attribute__((ext_vector_type(4))) int i32x4;
typedef __attribute__((ext_vector_type(2))) int i32x2;

#define CTR_BASE 106496

__device__ __forceinline__ short f2bf(float f) {
  unsigned u = __builtin_bit_cast(unsigned, f);
  u = (u + 0x7fffu + ((u >> 16) & 1u)) >> 16;
  return (short)u;
}
__device__ __forceinline__ float bf2f(short s) {
  unsigned u = ((unsigned)(unsigned short)s) << 16;
  return __builtin_bit_cast(float, u);
}
__device__ __forceinline__ int swzaddr(int base, int stride, int row, int colbyte) {
  return base + row * stride + (colbyte ^ (((row & 7) << 4) ^ ((row & 8) << 2)));
}
// Per-half soft barrier: 8 waves arrive (lane0 ds_add), spin until count>=target.
// Does NOT touch vmcnt (B prefetch stays in flight) and does NOT sync the other half.
__device__ __forceinline__ void halfbar(short* lds, int half, int target) {
  __builtin_amdgcn_sched_barrier(0);
  asm volatile("s_waitcnt lgkmcnt(0)" ::: "memory");
  int* ctr = (int*)((char*)lds + CTR_BASE + (half << 2));
  if ((threadIdx.x & 63) == 0) atomicAdd(ctr, 1);
  while (*(volatile int*)ctr < target) { __builtin_amdgcn_s_sleep(1); }
  asm volatile("" ::: "memory");
  __builtin_amdgcn_sched_barrier(0);
}

// ---------------- weight pack ----------------
// fp32 row-major (K,256) -> bf16 B-frag-major with INTERLEAVED columns:
// packet p = (kt*16 + nt)*64 + lane ; frag col j=lane&15 -> actual col
// n = (nt>>1)*32 + 2*j + (nt&1)
__global__ void pack_weights_kernel(const float* __restrict__ W1a, const float* __restrict__ W1b,
                                    const float* __restrict__ Wa, const float* __restrict__ Wb,
                                    short* __restrict__ ws) {
  int p = blockIdx.x * blockDim.x + threadIdx.x;
  const int P1 = 10240;           // W1a: 10 kt * 16 nt * 64
  const int P2 = P1 + 8192;       // W1b
  const int P3 = P2 + 8 * 18432;  // Wa
  const int P4 = P3 + 8 * 8192;   // Wb
  if (p >= P4) return;
  const float* src;
  int q;
  if (p < P1)      { src = W1a; q = p; }
  else if (p < P2) { src = W1b; q = p - P1; }
  else if (p < P3) { q = p - P2; int l = q / 18432; q -= l * 18432; src = Wa + l * 147456; }
  else             { q = p - P3; int l = q / 8192;  q -= l * 8192;  src = Wb + l * 65536; }
  const int lane = q & 63, t = q >> 6, nt = t & 15, kt = t >> 4;
  const int k0 = kt * 32 + ((lane >> 4) << 3);
  const int n  = ((nt >> 1) << 5) + ((lane & 15) << 1) + (nt & 1);
  short* dst = ws + (size_t)p * 8;
#pragma unroll
  for (int i = 0; i < 8; ++i) dst[i] = f2bf(src[(size_t)(k0 + i) * 256 + n]);
}

// ---------------- fused MLP ----------------
// LDS (bytes): xyz [0,40960) stride 640 ; x [40960,73728) stride 512 ;
//              t [73728,106496) stride 512 ; half-counters [106496,106504)
struct BPre { bfv8 b0, b1; };
struct AFrag { bfv8 r0, r1; };

__device__ __forceinline__ bfv8 bfrag(const short* __restrict__ wp, int kt, int nt, int lane) {
  const short* base = wp + (((size_t)(kt * 16 + nt)) << 9);  // wave-uniform
  return *(const bfv8*)(base + (lane << 3));                 // lane offset
}

template<int NKT, int SPLITKT, bool LEAKY>
__device__ __forceinline__ BPre do_gemm(short* lds,
    int a1Base, int a1S, int a2Base, int a2S,
    const short* __restrict__ wp, const short* __restrict__ wpn,
    const float* __restrict__ bias, int outBase,
    int wrb, int wc, int lane, BPre pre)
{
  const int lo = lane & 15, hi = lane >> 4;
  const int ntb = wc << 1;
  const float2 bv = *(const float2*)(bias + (wc << 5) + (lo << 1));
  f32x4 acc[2][2];
#pragma unroll
  for (int r = 0; r < 2; ++r) { acc[r][0] = (f32x4)0.f; acc[r][1] = (f32x4)0.f; }

  // Precomputed A bases: swizzle xor decomposes as base[kk&1] + (kk>>1)*128.
  const int xr  = ((lo & 7) << 4) ^ ((lo & 8) << 2);
  const int hib = hi << 4;
  const char* A1E = (const char*)lds + a1Base + (wrb + lo) * a1S + ((      hib) ^ xr);
  const char* A1O = (const char*)lds + a1Base + (wrb + lo) * a1S + ((64 + hib) ^ xr);
  const char* A2E = (const char*)lds + a2Base + (wrb + lo) * a2S + ((      hib) ^ xr);
  const char* A2O = (const char*)lds + a2Base + (wrb + lo) * a2S + ((64 + hib) ^ xr);

  bfv8 bst[2][2];
  AFrag ast[2];
  bst[0][0] = pre.b0; bst[0][1] = pre.b1;
  ast[0].r0 = *(const bfv8*)(A1E);
  ast[0].r1 = *(const bfv8*)(A1E + (a1S << 4));
  BPre nxt;

#pragma unroll
  for (int i = 0; i < NKT; ++i) {
    if (i + 1 < NKT) {
      bst[(i + 1) & 1][0] = bfrag(wp, i + 1, ntb, lane);
      bst[(i + 1) & 1][1] = bfrag(wp, i + 1, ntb + 1, lane);
      const int kt = i + 1;
      const int kk = (kt < SPLITKT) ? kt : kt - SPLITKT;
      const char* b = (kt < SPLITKT) ? ((kk & 1) ? A1O : A1E) : ((kk & 1) ? A2O : A2E);
      const int s  = (kt < SPLITKT) ? a1S : a2S;
      ast[(i + 1) & 1].r0 = *(const bfv8*)(b + (kk >> 1) * 128);
      ast[(i + 1) & 1].r1 = *(const bfv8*)(b + (kk >> 1) * 128 + (s << 4));
    } else {  // last iter: start next gemm's first B frags (fly over epilogue+barrier)
      nxt.b0 = bfrag(wpn, 0, ntb, lane);
      nxt.b1 = bfrag(wpn, 0, ntb + 1, lane);
    }
    __builtin_amdgcn_s_setprio(1);
    acc[0][0] = __builtin_amdgcn_mfma_f32_16x16x32_bf16(ast[i & 1].r0, bst[i & 1][0], acc[0][0], 0, 0, 0);
    acc[0][1] = __builtin_amdgcn_mfma_f32_16x16x32_bf16(ast[i & 1].r0, bst[i & 1][1], acc[0][1], 0, 0, 0);
    acc[1][0] = __builtin_amdgcn_mfma_f32_16x16x32_bf16(ast[i & 1].r1, bst[i & 1][0], acc[1][0], 0, 0, 0);
    acc[1][1] = __builtin_amdgcn_mfma_f32_16x16x32_bf16(ast[i & 1].r1, bst[i & 1][1], acc[1][1], 0, 0, 0);
    __builtin_amdgcn_s_setprio(0);
  }
  // epilogue: bias + leaky + cvt_pk(2 bf16) -> one b32 store per pair
#pragma unroll
  for (int rt = 0; rt < 2; ++rt)
#pragma unroll
    for (int rr = 0; rr < 4; ++rr) {
      float v0 = acc[rt][0][rr] + bv.x;
      float v1 = acc[rt][1][rr] + bv.y;
      if (LEAKY) { v0 = fmaxf(v0, 0.01f * v0); v1 = fmaxf(v1, 0.01f * v1); }
      unsigned pk;
      asm("v_cvt_pk_bf16_f32 %0, %1, %2" : "=v"(pk) : "v"(v0), "v"(v1));
      const int orow = wrb + (rt << 4) + (hi << 2) + rr;
      *(unsigned*)((char*)lds + swzaddr(outBase, 512, orow, (wc << 6) + (lo << 2))) = pk;
    }
  return nxt;
}

__launch_bounds__(1024, 1)
__global__ void geo2vec_kernel(const float* __restrict__ xy, const int* __restrict__ idx,
    const float* __restrict__ emb,
    const float* __restrict__ b1a, const float* __restrict__ b1b,
    const float* __restrict__ ba, const float* __restrict__ bb,
    const float* __restrict__ W2, const float* __restrict__ b2,
    const short* __restrict__ wp, float* __restrict__ out)
{
  __shared__ short lds[53256];  // 104 KB + 8B counters
  const int tid = threadIdx.x;
  const int wave = tid >> 6, lane = tid & 63;
  const int wr = wave >> 3;   // row half: 0 = rows 0-31, 1 = rows 32-63
  const int wc = __builtin_amdgcn_readfirstlane(wave & 7);
  const int wrb = wr << 5;

  // init per-half counters; the ONLY whole-block barrier in the kernel
  if (tid == 0) { *(int*)((char*)lds + CTR_BASE) = 0; *(int*)((char*)lds + CTR_BASE + 4) = 0; }
  __syncthreads();

  // issue first gemm's B stage-0 loads immediately: hide under prologue trig
  BPre pre;
  pre.b0 = bfrag(wp, 0, (wc << 1), lane);
  pre.b1 = bfrag(wp, 0, (wc << 1) + 1, lane);

  // ---- prologue: pos-encode + gather z; each half writes ONLY its own rows ----
  {
    const int g = tid >> 4, j = tid & 15;  // row g: tids 0-511 -> rows 0-31 (= half wr)
    const int row = blockIdx.x * 64 + g;
    const float xv = xy[2 * row], yv = xy[2 * row + 1];
    const float rv = sqrtf(xv * xv + yv * yv);
    union { short sh[4]; i32x2 v; } tmp;
#pragma unroll
    for (int i = 0; i < 4; ++i) {
      const int c = 4 * j + i;
      float fv;
      if (c < 2)       fv = c ? yv : xv;
      else if (c < 22) { int m = c - 2;  float f = 1.0f + (5.0f / 9.0f) * (m >> 1); fv = sinf(((m & 1) ? yv : xv) * f); }
      else if (c < 42) { int m = c - 22; float f = 1.0f + (5.0f / 9.0f) * (m >> 1); fv = cosf(((m & 1) ? yv : xv) * f); }
      else if (c < 44) fv = (c == 42) ? xv : yv;
      else if (c < 54) fv = sinf(rv * (1.0f + (5.0f / 9.0f) * (c - 44)));
      else             fv = cosf(rv * (1.0f + (5.0f / 9.0f) * (c - 54)));
      tmp.sh[i] = f2bf(fv);
    }
    *(i32x2*)((char*)lds + swzaddr(0, 640, g, j << 3)) = tmp.v;
    const float* zr = emb + (size_t)(unsigned)idx[row] * 256;
#pragma unroll
    for (int c8 = 0; c8 < 2; ++c8) {
      const int cel = j * 16 + c8 * 8;
      const float4 f0 = *(const float4*)(zr + cel);
      const float4 f1 = *(const float4*)(zr + cel + 4);
      union { short sh[8]; i32x4 v; } t2;
      t2.sh[0] = f2bf(f0.x); t2.sh[1] = f2bf(f0.y); t2.sh[2] = f2bf(f0.z); t2.sh[3] = f2bf(f0.w);
      t2.sh[4] = f2bf(f1.x); t2.sh[5] = f2bf(f1.y); t2.sh[6] = f2bf(f1.z); t2.sh[7] = f2bf(f1.w);
      *(i32x4*)((char*)lds + swzaddr(0, 640, g, (64 + cel) << 1)) = t2.v;
    }
  }
  halfbar(lds, wr, 8);   // phase 1: own half's xyz ready

  // layer 1
  pre = do_gemm<10, 10, true >(lds, 0, 640, 0, 640,         wp,         wp + 81920,  b1a, 73728, wrb, wc, lane, pre);
  halfbar(lds, wr, 16);
  pre = do_gemm<8,  8,  false>(lds, 73728, 512, 73728, 512, wp + 81920, wp + 147456, b1b, 40960, wrb, wc, lane, pre);
  halfbar(lds, wr, 24);
  // 8 mid layers
  for (int l = 0; l < 8; ++l) {
    const short* wa = wp + 147456 + l * 147456;
    const short* wb = wp + 1327104 + l * 65536;
    const short* wan = (l < 7) ? (wa + 147456) : wp;  // dummy (valid mem) on last layer
    pre = do_gemm<18, 10, true >(lds, 0, 640, 40960, 512,     wa, wb,  ba + l * 256, 73728, wrb, wc, lane, pre);
    halfbar(lds, wr, 32 + l * 16);
    pre = do_gemm<8,  8,  false>(lds, 73728, 512, 73728, 512, wb, wan, bb + l * 256, 40960, wrb, wc, lane, pre);
    halfbar(lds, wr, 40 + l * 16);
  }
  // final: out = x @ W2 + b2 ; rows of own half only (tid>>4 matches half)
  {
    const int r = tid >> 4, j = tid & 15;
    float sum = 0.f;
#pragma unroll
    for (int h = 0; h < 2; ++h) {
      const int cb = 32 * j + 16 * h;
      const s16x8 v = *(const s16x8*)((const char*)lds + swzaddr(40960, 512, r, cb));
      const int c0 = 16 * j + 8 * h;
      const float4 w0 = *(const float4*)(W2 + c0);
      const float4 w1 = *(const float4*)(W2 + c0 + 4);
      sum += bf2f(v[0]) * w0.x + bf2f(v[1]) * w0.y + bf2f(v[2]) * w0.z + bf2f(v[3]) * w0.w;
      sum += bf2f(v[4]) * w1.x + bf2f(v[5]) * w1.y + bf2f(v[6]) * w1.z + bf2f(v[7]) * w1.w;
    }
    sum += __shfl_xor(sum, 1); sum += __shfl_xor(sum, 2);
    sum += __shfl_xor(sum, 4); sum += __shfl_xor(sum, 8);
    if (j == 0) out[blockIdx.x * 64 + r] = sum + b2[0];
  }
}

extern "C" void kernel_launch(void* const* d_in, const int* in_sizes, int n_in,
                              void* d_out, int out_size, void* d_ws, size_t ws_size,
                              hipStream_t stream) {
  const float* xy  = (const float*)d_in[0];
  const int*   idx = (const int*)d_in[1];
  const float* emb = (const float*)d_in[2];
  const float* W1a = (const float*)d_in[3];
  const float* b1a = (const float*)d_in[4];
  const float* W1b = (const float*)d_in[5];
  const float* b1b = (const float*)d_in[6];
  const float* Wa  = (const float*)d_in[7];
  const float* ba  = (const float*)d_in[8];
  const float* Wb  = (const float*)d_in[9];
  const float* bb  = (const float*)d_in[10];
  const float* W2  = (const float*)d_in[11];
  const float* b2  = (const float*)d_in[12];
  short* ws = (short*)d_ws;
  const int B = in_sizes[1];

  hipLaunchKernelGGL(pack_weights_kernel, dim3(904), dim3(256), 0, stream,
                     W1a, W1b, Wa, Wb, ws);
  hipLaunchKernelGGL(geo2vec_kernel, dim3(B / 64), dim3(1024), 0, stream,
                     xy, idx, emb, b1a, b1b, ba, bb, W2, b2, ws, (float*)d_out);
}

// Round 14
// 472.975 us; speedup vs baseline: 1.5827x; 1.2645x over previous
//
#include <hip/hip_runtime.h>
#include <hip/hip_bf16.h>

// Geo2Vec fused MLP, bf16 MFMA. Round 14: 512 threads, 8 waves, wave tile =
// 64 rows x 32 cols (ONE row-group -> B-L2 traffic halved vs 16-wave 32-row
// layout; B/A/MFMA streams all ~= the 310cyc/kt MFMA cadence). The 512-thread
// VGPR budget (~112, vs the hard 64 cap at 1024 thr) finally fits real
// pipelines: acc 32 + 2-deep A (32) + 3-deep B (24) + next-gemm B (8).

typedef __attribute__((ext_vector_type(8))) __bf16 bfv8;
typedef __attribute__((ext_vector_type(8))) short s16x8;
typedef __attribute__((ext_vector_type(4))) float f32x4;
typedef __attribute__((ext_vector_type(4))) int i32x4;

__device__ __forceinline__ short f2bf(float f) {
  unsigned u = __builtin_bit_cast(unsigned, f);
  u = (u + 0x7fffu + ((u >> 16) & 1u)) >> 16;
  return (short)u;
}
__device__ __forceinline__ float bf2f(short s) {
  unsigned u = ((unsigned)(unsigned short)s) << 16;
  return __builtin_bit_cast(float, u);
}
__device__ __forceinline__ int swzaddr(int base, int stride, int row, int colbyte) {
  return base + row * stride + (colbyte ^ (((row & 7) << 4) ^ ((row & 8) << 2)));
}
// LDS-visibility barrier that does NOT drain vmcnt (keeps B prefetch in flight).
__device__ __forceinline__ void ldsbar() {
  __builtin_amdgcn_sched_barrier(0);
  asm volatile("s_waitcnt lgkmcnt(0)");
  __builtin_amdgcn_s_barrier();
  __builtin_amdgcn_sched_barrier(0);
}

// ---------------- weight pack ----------------
// fp32 row-major (K,256) -> bf16 B-frag-major with INTERLEAVED columns:
// packet p = (kt*16 + nt)*64 + lane ; frag col j=lane&15 -> actual col
// n = (nt>>1)*32 + 2*j + (nt&1)   (epilogue cvt_pk un-interleaves)
__global__ void pack_weights_kernel(const float* __restrict__ W1a, const float* __restrict__ W1b,
                                    const float* __restrict__ Wa, const float* __restrict__ Wb,
                                    short* __restrict__ ws) {
  int p = blockIdx.x * blockDim.x + threadIdx.x;
  const int P1 = 10240;           // W1a: 10 kt * 16 nt * 64
  const int P2 = P1 + 8192;       // W1b
  const int P3 = P2 + 8 * 18432;  // Wa
  const int P4 = P3 + 8 * 8192;   // Wb
  if (p >= P4) return;
  const float* src;
  int q;
  if (p < P1)      { src = W1a; q = p; }
  else if (p < P2) { src = W1b; q = p - P1; }
  else if (p < P3) { q = p - P2; int l = q / 18432; q -= l * 18432; src = Wa + l * 147456; }
  else             { q = p - P3; int l = q / 8192;  q -= l * 8192;  src = Wb + l * 65536; }
  const int lane = q & 63, t = q >> 6, nt = t & 15, kt = t >> 4;
  const int k0 = kt * 32 + ((lane >> 4) << 3);
  const int n  = ((nt >> 1) << 5) + ((lane & 15) << 1) + (nt & 1);
  short* dst = ws + (size_t)p * 8;
#pragma unroll
  for (int i = 0; i < 8; ++i) dst[i] = f2bf(src[(size_t)(k0 + i) * 256 + n]);
}

// ---------------- fused MLP ----------------
// LDS (bytes): xyz [0,40960) stride 640 ; x [40960,73728) stride 512 ;
//              t [73728,106496) stride 512
struct BPre { bfv8 b0, b1; };
struct AFrag { bfv8 r0, r1, r2, r3; };

__device__ __forceinline__ bfv8 bfrag(const short* __restrict__ wp, int kt, int nt, int lane) {
  const short* base = wp + (((size_t)(kt * 16 + nt)) << 9);  // wave-uniform
  return *(const bfv8*)(base + (lane << 3));
}

template<int NKT, int SPLITKT, bool LEAKY>
__device__ __forceinline__ BPre do_gemm(short* lds,
    int a1Base, int a1S, int a2Base, int a2S,
    const short* __restrict__ wp, const short* __restrict__ wpn,
    const float* __restrict__ bias, int outBase,
    int wc, int lane, BPre pre)
{
  const int lo = lane & 15, hi = lane >> 4;
  const int ntb = wc << 1;
  const float2 bv = *(const float2*)(bias + (wc << 5) + (lo << 1));
  f32x4 acc[4][2];
#pragma unroll
  for (int r = 0; r < 4; ++r) { acc[r][0] = (f32x4)0.f; acc[r][1] = (f32x4)0.f; }

  // Decomposed swizzle bases: addr = base[kk&1] + (kk>>1)*128 + rt*(stride*16)
  const int xr  = ((lo & 7) << 4) ^ ((lo & 8) << 2);
  const int hib = hi << 4;
  const char* A1E = (const char*)lds + a1Base + lo * a1S + ((     hib) ^ xr);
  const char* A1O = (const char*)lds + a1Base + lo * a1S + ((64 + hib) ^ xr);
  const char* A2E = (const char*)lds + a2Base + lo * a2S + ((     hib) ^ xr);
  const char* A2O = (const char*)lds + a2Base + lo * a2S + ((64 + hib) ^ xr);

  bfv8 bst[3][2];
  AFrag ast[2];
  bst[0][0] = pre.b0; bst[0][1] = pre.b1;
  if (NKT > 1) {
    bst[1][0] = bfrag(wp, 1, ntb, lane);
    bst[1][1] = bfrag(wp, 1, ntb + 1, lane);
  }
  ast[0].r0 = *(const bfv8*)(A1E);
  ast[0].r1 = *(const bfv8*)(A1E + (a1S << 4));
  ast[0].r2 = *(const bfv8*)(A1E + (a1S << 5));
  ast[0].r3 = *(const bfv8*)(A1E + (a1S << 4) * 3);
  BPre nxt;

#pragma unroll
  for (int i = 0; i < NKT; ++i) {
    if (i + 2 < NKT) {
      bst[(i + 2) % 3][0] = bfrag(wp, i + 2, ntb, lane);
      bst[(i + 2) % 3][1] = bfrag(wp, i + 2, ntb + 1, lane);
    } else if (i + 2 == NKT || (NKT == 1 && i == 0)) {  // next gemm's first B frags
      nxt.b0 = bfrag(wpn, 0, ntb, lane);
      nxt.b1 = bfrag(wpn, 0, ntb + 1, lane);
    }
    if (i + 1 < NKT) {  // A one kt ahead, static slot
      const int kt2 = i + 1;
      const bool g1 = kt2 < SPLITKT;
      const int kk  = g1 ? kt2 : kt2 - SPLITKT;
      const int st  = g1 ? a1S : a2S;
      const char* b = (g1 ? ((kk & 1) ? A1O : A1E) : ((kk & 1) ? A2O : A2E)) + (kk >> 1) * 128;
      AFrag& an = ast[(i + 1) & 1];
      an.r0 = *(const bfv8*)(b);
      an.r1 = *(const bfv8*)(b + (st << 4));
      an.r2 = *(const bfv8*)(b + (st << 5));
      an.r3 = *(const bfv8*)(b + (st << 4) * 3);
    }
    const AFrag& ac = ast[i & 1];
    __builtin_amdgcn_s_setprio(1);
    acc[0][0] = __builtin_amdgcn_mfma_f32_16x16x32_bf16(ac.r0, bst[i % 3][0], acc[0][0], 0, 0, 0);
    acc[0][1] = __builtin_amdgcn_mfma_f32_16x16x32_bf16(ac.r0, bst[i % 3][1], acc[0][1], 0, 0, 0);
    acc[1][0] = __builtin_amdgcn_mfma_f32_16x16x32_bf16(ac.r1, bst[i % 3][0], acc[1][0], 0, 0, 0);
    acc[1][1] = __builtin_amdgcn_mfma_f32_16x16x32_bf16(ac.r1, bst[i % 3][1], acc[1][1], 0, 0, 0);
    acc[2][0] = __builtin_amdgcn_mfma_f32_16x16x32_bf16(ac.r2, bst[i % 3][0], acc[2][0], 0, 0, 0);
    acc[2][1] = __builtin_amdgcn_mfma_f32_16x16x32_bf16(ac.r2, bst[i % 3][1], acc[2][1], 0, 0, 0);
    acc[3][0] = __builtin_amdgcn_mfma_f32_16x16x32_bf16(ac.r3, bst[i % 3][0], acc[3][0], 0, 0, 0);
    acc[3][1] = __builtin_amdgcn_mfma_f32_16x16x32_bf16(ac.r3, bst[i % 3][1], acc[3][1], 0, 0, 0);
    __builtin_amdgcn_s_setprio(0);
  }
  // epilogue: bias + leaky + cvt_pk(2 bf16) -> one b32 store per pair
#pragma unroll
  for (int rt = 0; rt < 4; ++rt)
#pragma unroll
    for (int rr = 0; rr < 4; ++rr) {
      float v0 = acc[rt][0][rr] + bv.x;
      float v1 = acc[rt][1][rr] + bv.y;
      if (LEAKY) { v0 = fmaxf(v0, 0.01f * v0); v1 = fmaxf(v1, 0.01f * v1); }
      unsigned pk;
      asm("v_cvt_pk_bf16_f32 %0, %1, %2" : "=v"(pk) : "v"(v0), "v"(v1));
      const int orow = (rt << 4) + (hi << 2) + rr;
      *(unsigned*)((char*)lds + swzaddr(outBase, 512, orow, (wc << 6) + (lo << 2))) = pk;
    }
  return nxt;
}

__launch_bounds__(512, 1)
__global__ void geo2vec_kernel(const float* __restrict__ xy, const int* __restrict__ idx,
    const float* __restrict__ emb,
    const float* __restrict__ b1a, const float* __restrict__ b1b,
    const float* __restrict__ ba, const float* __restrict__ bb,
    const float* __restrict__ W2, const float* __restrict__ b2,
    const short* __restrict__ wp, float* __restrict__ out)
{
  __shared__ short lds[53248];  // 104 KB
  const int tid = threadIdx.x;
  const int lane = tid & 63;
  const int wc = __builtin_amdgcn_readfirstlane(tid >> 6);  // wave = col group

  // issue first gemm's B stage-0 loads immediately: hide under prologue trig
  BPre pre;
  pre.b0 = bfrag(wp, 0, (wc << 1), lane);
  pre.b1 = bfrag(wp, 0, (wc << 1) + 1, lane);

  // ---- prologue: pos-encode + gather z -> xyz tile (64 x 320 bf16) ----
  {
    const int g = tid >> 3, j = tid & 7;  // 8 threads per row
    const int row = blockIdx.x * 64 + g;
    const float xv = xy[2 * row], yv = xy[2 * row + 1];
    const float rv = sqrtf(xv * xv + yv * yv);
    union { short s[8]; i32x4 v; } tmp;
#pragma unroll
    for (int i = 0; i < 8; ++i) {
      const int c = 8 * j + i;
      float fv;
      if (c < 2)       fv = c ? yv : xv;
      else if (c < 22) { int m = c - 2;  float f = 1.0f + (5.0f / 9.0f) * (m >> 1); fv = sinf(((m & 1) ? yv : xv) * f); }
      else if (c < 42) { int m = c - 22; float f = 1.0f + (5.0f / 9.0f) * (m >> 1); fv = cosf(((m & 1) ? yv : xv) * f); }
      else if (c < 44) fv = (c == 42) ? xv : yv;
      else if (c < 54) fv = sinf(rv * (1.0f + (5.0f / 9.0f) * (c - 44)));
      else             fv = cosf(rv * (1.0f + (5.0f / 9.0f) * (c - 54)));
      tmp.s[i] = f2bf(fv);
    }
    *(i32x4*)((char*)lds + swzaddr(0, 640, g, j << 4)) = tmp.v;
    const float* zr = emb + (size_t)(unsigned)idx[row] * 256;
#pragma unroll
    for (int c4 = 0; c4 < 4; ++c4) {
      const int cel = j * 32 + c4 * 8;
      const float4 f0 = *(const float4*)(zr + cel);
      const float4 f1 = *(const float4*)(zr + cel + 4);
      union { short s[8]; i32x4 v; } t2;
      t2.s[0] = f2bf(f0.x); t2.s[1] = f2bf(f0.y); t2.s[2] = f2bf(f0.z); t2.s[3] = f2bf(f0.w);
      t2.s[4] = f2bf(f1.x); t2.s[5] = f2bf(f1.y); t2.s[6] = f2bf(f1.z); t2.s[7] = f2bf(f1.w);
      *(i32x4*)((char*)lds + swzaddr(0, 640, g, (64 + cel) << 1)) = t2.v;
    }
  }
  ldsbar();

  // layer 1
  pre = do_gemm<10, 10, true >(lds, 0, 640, 0, 640,         wp,         wp + 81920,  b1a, 73728, wc, lane, pre);
  ldsbar();
  pre = do_gemm<8,  8,  false>(lds, 73728, 512, 73728, 512, wp + 81920, wp + 147456, b1b, 40960, wc, lane, pre);
  ldsbar();
  // 8 mid layers
  for (int l = 0; l < 8; ++l) {
    const short* wa = wp + 147456 + l * 147456;
    const short* wb = wp + 1327104 + l * 65536;
    const short* wan = (l < 7) ? (wa + 147456) : wp;  // dummy (valid mem) on last layer
    pre = do_gemm<18, 10, true >(lds, 0, 640, 40960, 512,     wa, wb,  ba + l * 256, 73728, wc, lane, pre);
    ldsbar();
    pre = do_gemm<8,  8,  false>(lds, 73728, 512, 73728, 512, wb, wan, bb + l * 256, 40960, wc, lane, pre);
    ldsbar();
  }
  // final: out = x @ W2 + b2 ; 8 threads per row (32 cols each), width-8 reduce
  {
    const int r = tid >> 3, j = tid & 7;
    float sum = 0.f;
#pragma unroll
    for (int h = 0; h < 4; ++h) {
      const int cb = 64 * j + 16 * h;
      const s16x8 v = *(const s16x8*)((const char*)lds + swzaddr(40960, 512, r, cb));
      const int c0 = 32 * j + 8 * h;
      const float4 w0 = *(const float4*)(W2 + c0);
      const float4 w1 = *(const float4*)(W2 + c0 + 4);
      sum += bf2f(v[0]) * w0.x + bf2f(v[1]) * w0.y + bf2f(v[2]) * w0.z + bf2f(v[3]) * w0.w;
      sum += bf2f(v[4]) * w1.x + bf2f(v[5]) * w1.y + bf2f(v[6]) * w1.z + bf2f(v[7]) * w1.w;
    }
    sum += __shfl_xor(sum, 1); sum += __shfl_xor(sum, 2); sum += __shfl_xor(sum, 4);
    if (j == 0) out[blockIdx.x * 64 + r] = sum + b2[0];
  }
}

extern "C" void kernel_launch(void* const* d_in, const int* in_sizes, int n_in,
                              void* d_out, int out_size, void* d_ws, size_t ws_size,
                              hipStream_t stream) {
  const float* xy  = (const float*)d_in[0];
  const int*   idx = (const int*)d_in[1];
  const float* emb = (const float*)d_in[2];
  const float* W1a = (const float*)d_in[3];
  const float* b1a = (const float*)d_in[4];
  const float* W1b = (const float*)d_in[5];
  const float* b1b = (const float*)d_in[6];
  const float* Wa  = (const float*)d_in[7];
  const float* ba  = (const float*)d_in[8];
  const float* Wb  = (const float*)d_in[9];
  const float* bb  = (const float*)d_in[10];
  const float* W2  = (const float*)d_in[11];
  const float* b2  = (const float*)d_in[12];
  short* ws = (short*)d_ws;
  const int B = in_sizes[1];

  hipLaunchKernelGGL(pack_weights_kernel, dim3(904), dim3(256), 0, stream,
                     W1a, W1b, Wa, Wb, ws);
  hipLaunchKernelGGL(geo2vec_kernel, dim3(B / 64), dim3(512), 0, stream,
                     xy, idx, emb, b1a, b1b, ba, bb, W2, b2, ws, (float*)d_out);
}